// Round 1
// 282.271 us; speedup vs baseline: 1.0992x; 1.0992x over previous
//
#include <hip/hip_runtime.h>

#define NPTS 8192

typedef __bf16 bf16x8 __attribute__((ext_vector_type(8)));
typedef short short8 __attribute__((ext_vector_type(8)));
typedef float f32x4 __attribute__((ext_vector_type(4)));

// ws layout (floats): yc [0,131072) ; wtr [131072,196608) ; wti [196608,262144)
// d_out scratch layout (floats):
//   Xp  [0, 2097152): partial DFT, Xp[((seg*16+k)*2+c)*4096 + row], seg<16,
//       c=0 re / 1 im, row = b*64 + in_ch
//   bas [2097152, 2359296): bf16 basis tables as ushort bits:
//       hi[262144] then lo[262144], fragment-order:
//       idx = ((ct*256 + gk)*64 + lane)*8 + j  ->  mode m = (ct*16)+(lane&15),
//       n = gk*32 + ((lane>>4)&3)*8 + j ; ct=0: cos, ct=1: -sin
// Order: prep writes bas -> dft reads bas, writes Xp -> mix reads Xp ->
// synth overwrites all of d_out.

__global__ __launch_bounds__(256) void prep_kernel(const float* __restrict__ wr,
                                                   const float* __restrict__ wi,
                                                   float* __restrict__ wtr,
                                                   float* __restrict__ wti,
                                                   ushort* __restrict__ bas) {
    const int bid = blockIdx.x, t = threadIdx.x;
    if (bid < 256) {
        int idx = bid * 256 + t;                    // [0, 65536)
        int i = idx >> 10, o = (idx >> 4) & 63, k = idx & 15;
        int dst = k * 4096 + i * 64 + o;
        wtr[dst] = wr[idx];
        wti[dst] = wi[idx];
    } else {
        int e = (bid - 256) * 256 + t;              // [0, 262144)
        int j = e & 7;
        int lane = (e >> 3) & 63;
        int gk = (e >> 9) & 255;
        int ct = e >> 17;                           // 0: cos tile, 1: -sin tile
        int m = lane & 15;
        int n = gk * 32 + ((lane >> 4) & 3) * 8 + j;
        int p = (m * n) & 8191;
        float a = (float)p * (1.0f / 4096.0f);
        float v = ct ? -sinpif(a) : cospif(a);
        // RNE bf16 hi + RNE bf16 residual lo
        unsigned u = __float_as_uint(v);
        unsigned hb = (u + 0x7fffu + ((u >> 16) & 1u)) >> 16;
        float hf = __uint_as_float(hb << 16);
        float lo = v - hf;
        unsigned ul = __float_as_uint(lo);
        unsigned lb = (ul + 0x7fffu + ((ul >> 16) & 1u)) >> 16;
        bas[e] = (ushort)hb;
        bas[262144 + e] = (ushort)lb;
    }
}

// Stage 1: truncated DFT as MFMA GEMM.
// grid 1024 = 64 row-blocks(64 rows) x 16 k-segments(512 pts).
// Wave owns 16 rows; A = x rows (bf16 hi/lo split), B = basis fragments.
// D = A*B: col(lane&15)=mode, row((lane>>4)*4+reg) -> float4 store to Xp.
__global__ __launch_bounds__(256) void dft_kernel(const float* __restrict__ x,
                                                  const ushort* __restrict__ bas,
                                                  float* __restrict__ Xp) {
    const int t = threadIdx.x;
    const int lane = t & 63, w = t >> 6;
    const int rb = blockIdx.x >> 4, seg = blockIdx.x & 15;
    const int rowq = lane >> 4;                     // 0..3 (k-slot quarter)
    const int row = rb * 64 + w * 16 + (lane & 15);
    const float* xp = x + (size_t)row * NPTS + seg * 512 + rowq * 8;
    const bf16x8* bh = (const bf16x8*)bas;
    const bf16x8* bl = (const bf16x8*)(bas + 262144);
    const int gk0 = seg * 16;

    f32x4 acc0 = {0.f, 0.f, 0.f, 0.f};             // cos tile  (re)
    f32x4 acc1 = {0.f, 0.f, 0.f, 0.f};             // -sin tile (im)

    float4 xa = *(const float4*)xp;
    float4 xb = *(const float4*)(xp + 4);
    bf16x8 c0h = bh[gk0 * 64 + lane];
    bf16x8 c1h = bh[(256 + gk0) * 64 + lane];
    bf16x8 c0l = bl[gk0 * 64 + lane];
    bf16x8 c1l = bl[(256 + gk0) * 64 + lane];

    for (int ks = 0; ks < 16; ++ks) {
        // split x into bf16 hi (truncate) + bf16 lo (RNE of residual)
        short8 hsv, lsv;
        {
            float v[8] = {xa.x, xa.y, xa.z, xa.w, xb.x, xb.y, xb.z, xb.w};
#pragma unroll
            for (int j = 0; j < 8; ++j) {
                unsigned u = __float_as_uint(v[j]);
                hsv[j] = (short)(u >> 16);
                float lo = v[j] - __uint_as_float(u & 0xffff0000u);
                unsigned ul = __float_as_uint(lo);
                lsv[j] = (short)((ul + 0x7fffu + ((ul >> 16) & 1u)) >> 16);
            }
        }
        bf16x8 ah = __builtin_bit_cast(bf16x8, hsv);
        bf16x8 al = __builtin_bit_cast(bf16x8, lsv);

        // depth-1 prefetch of next k-step (x + 4 basis fragments)
        float4 nxa, nxb;
        bf16x8 n0h, n1h, n0l, n1l;
        if (ks < 15) {
            const float* xq = xp + (ks + 1) * 32;
            nxa = *(const float4*)xq;
            nxb = *(const float4*)(xq + 4);
            int gk = gk0 + ks + 1;
            n0h = bh[gk * 64 + lane];
            n1h = bh[(256 + gk) * 64 + lane];
            n0l = bl[gk * 64 + lane];
            n1l = bl[(256 + gk) * 64 + lane];
        }

        // D = xh*bh + xl*bh + xh*bl   (drop lo*lo, ~2^-18 rel)
        acc0 = __builtin_amdgcn_mfma_f32_16x16x32_bf16(ah, c0h, acc0, 0, 0, 0);
        acc1 = __builtin_amdgcn_mfma_f32_16x16x32_bf16(ah, c1h, acc1, 0, 0, 0);
        acc0 = __builtin_amdgcn_mfma_f32_16x16x32_bf16(al, c0h, acc0, 0, 0, 0);
        acc1 = __builtin_amdgcn_mfma_f32_16x16x32_bf16(al, c1h, acc1, 0, 0, 0);
        acc0 = __builtin_amdgcn_mfma_f32_16x16x32_bf16(ah, c0l, acc0, 0, 0, 0);
        acc1 = __builtin_amdgcn_mfma_f32_16x16x32_bf16(ah, c1l, acc1, 0, 0, 0);

        if (ks < 15) {
            xa = nxa; xb = nxb;
            c0h = n0h; c1h = n1h; c0l = n0l; c1l = n1l;
        }
    }

    const int k = lane & 15;
    const int rbase = rb * 64 + w * 16 + rowq * 4;  // 4 consecutive rows
    *(f32x4*)&Xp[(size_t)((seg * 16 + k) * 2 + 0) * 4096 + rbase] = acc0;
    *(f32x4*)&Xp[(size_t)((seg * 16 + k) * 2 + 1) * 4096 + rbase] = acc1;
}

// Stage 2: channel mix. grid 64 = 16 modes x 4 batch-quarters.
__global__ __launch_bounds__(256) void mix_kernel(const float* __restrict__ Xp,
                                                  const float* __restrict__ wtr,
                                                  const float* __restrict__ wti,
                                                  float* __restrict__ yc) {
    __shared__ float xre[16 * 65], xim[16 * 65];
    __shared__ float wlr[4096], wli[4096];
    const int t = threadIdx.x;
    const int k = blockIdx.x & 15, bq = blockIdx.x >> 4;
#pragma unroll
    for (int j = 0; j < 4; ++j) {
        int lr = t + j * 256;                   // local row [0,1024)
        int row = bq * 1024 + lr;
        float re = 0.f, im = 0.f;
#pragma unroll
        for (int s = 0; s < 16; ++s) {          // 16 K-segments now
            re += Xp[((s * 16 + k) * 2 + 0) * 4096 + row];
            im += Xp[((s * 16 + k) * 2 + 1) * 4096 + row];
        }
        xre[(lr >> 6) * 65 + (lr & 63)] = re;
        xim[(lr >> 6) * 65 + (lr & 63)] = im;
        ((float4*)wlr)[t + j * 256] = ((const float4*)(wtr + k * 4096))[t + j * 256];
        ((float4*)wli)[t + j * 256] = ((const float4*)(wti + k * 4096))[t + j * 256];
    }
    __syncthreads();
    const int bt = t >> 4;                      // local batch 0..15
    const int o4 = t & 15;                      // out_ch quad
    float accr[4] = {0.f, 0.f, 0.f, 0.f}, acci[4] = {0.f, 0.f, 0.f, 0.f};
    for (int i = 0; i < 64; ++i) {
        float xr = xre[bt * 65 + i], xi = xim[bt * 65 + i];
        float4 w4r = ((const float4*)wlr)[i * 16 + o4];
        float4 w4i = ((const float4*)wli)[i * 16 + o4];
        accr[0] += xr * w4r.x - xi * w4i.x;  acci[0] += xr * w4i.x + xi * w4r.x;
        accr[1] += xr * w4r.y - xi * w4i.y;  acci[1] += xr * w4i.y + xi * w4r.y;
        accr[2] += xr * w4r.z - xi * w4i.z;  acci[2] += xr * w4i.z + xi * w4r.z;
        accr[3] += xr * w4r.w - xi * w4i.w;  acci[3] += xr * w4i.w + xi * w4r.w;
    }
    const float invn = 1.0f / 8192.0f;
#pragma unroll
    for (int oo = 0; oo < 4; ++oo) {
        int row = (bq * 16 + bt) * 64 + o4 * 4 + oo;
        if (k == 0) {
            yc[row * 32]      = accr[oo] * invn;
            yc[row * 32 + 16] = 0.f;
        } else {
            yc[row * 32 + k]      = 2.f * accr[oo] * invn;
            yc[row * 32 + 16 + k] = -2.f * acci[oo] * invn;
        }
    }
}

// Stage 3: synthesis. grid 4096 = 256 row-groups(16 rows) x 16 n-tiles(512).
// Thread owns 2 n-points: basis = 64 VGPRs (cospif k=1 + complex-mul chain).
// Coefs staged in LDS, read as float4 broadcasts (conflict-free).
__global__ __launch_bounds__(256) void synth_kernel(const float* __restrict__ yc,
                                                    float* __restrict__ out) {
    __shared__ float cf[512];        // 16 rows x 32 coefs
    const int t = threadIdx.x;
    const int rg = blockIdx.x >> 4, tile = blockIdx.x & 15;
    cf[t]       = yc[rg * 512 + t];
    cf[t + 256] = yc[rg * 512 + 256 + t];

    const int n0 = tile * 512 + t * 2;
    float2 cb[16], sb[16];
    cb[0] = make_float2(1.f, 1.f);
    sb[0] = make_float2(0.f, 0.f);
    {
        float a0 = (float)(n0 & 8191) * (1.0f / 4096.0f);
        float a1 = (float)((n0 + 1) & 8191) * (1.0f / 4096.0f);
        cb[1] = make_float2(cospif(a0), cospif(a1));
        sb[1] = make_float2(sinpif(a0), sinpif(a1));
    }
#pragma unroll
    for (int k = 2; k < 16; ++k) {
        cb[k] = make_float2(cb[k-1].x * cb[1].x - sb[k-1].x * sb[1].x,
                            cb[k-1].y * cb[1].y - sb[k-1].y * sb[1].y);
        sb[k] = make_float2(sb[k-1].x * cb[1].x + cb[k-1].x * sb[1].x,
                            sb[k-1].y * cb[1].y + cb[k-1].y * sb[1].y);
    }
    __syncthreads();
#pragma unroll 4
    for (int r = 0; r < 16; ++r) {
        const float4* c4 = (const float4*)&cf[r * 32];
        float ax = 0.f, ay = 0.f;
#pragma unroll
        for (int j = 0; j < 4; ++j) {
            float4 a = c4[j];            // cos coefs k = 4j..4j+3
            float4 s = c4[4 + j];        // sin coefs
            ax += a.x * cb[4*j].x + a.y * cb[4*j+1].x + a.z * cb[4*j+2].x + a.w * cb[4*j+3].x
                + s.x * sb[4*j].x + s.y * sb[4*j+1].x + s.z * sb[4*j+2].x + s.w * sb[4*j+3].x;
            ay += a.x * cb[4*j].y + a.y * cb[4*j+1].y + a.z * cb[4*j+2].y + a.w * cb[4*j+3].y
                + s.x * sb[4*j].y + s.y * sb[4*j+1].y + s.z * sb[4*j+2].y + s.w * sb[4*j+3].y;
        }
        *(float2*)&out[(rg * 16 + r) * NPTS + n0] = make_float2(ax, ay);
    }
}

extern "C" void kernel_launch(void* const* d_in, const int* in_sizes, int n_in,
                              void* d_out, int out_size, void* d_ws, size_t ws_size,
                              hipStream_t stream) {
    const float* x  = (const float*)d_in[0];
    const float* wr = (const float*)d_in[1];
    const float* wi = (const float*)d_in[2];
    float* out = (float*)d_out;
    float* ws  = (float*)d_ws;
    float* yc  = ws;
    float* wtr = ws + 131072;
    float* wti = ws + 196608;
    float* Xp  = out;                                // 8 MB scratch
    ushort* bas = (ushort*)(out + 2097152);          // 1 MB bf16 basis tables

    prep_kernel<<<1280, 256, 0, stream>>>(wr, wi, wtr, wti, bas);
    dft_kernel<<<1024, 256, 0, stream>>>(x, bas, Xp);
    mix_kernel<<<64, 256, 0, stream>>>(Xp, wtr, wti, yc);
    synth_kernel<<<4096, 256, 0, stream>>>(yc, out);
}

// Round 2
// 258.286 us; speedup vs baseline: 1.2013x; 1.0929x over previous
//
#include <hip/hip_runtime.h>

#define NPTS 8192

typedef __bf16 bf16x8 __attribute__((ext_vector_type(8)));
typedef short short8 __attribute__((ext_vector_type(8)));
typedef float f32x4 __attribute__((ext_vector_type(4)));

// ws layout (floats): yc [0,131072) ; wtr [131072,196608) ; wti [196608,262144)
// d_out scratch layout (floats):
//   Xp  [0, 2097152): partial DFT, Xp[((seg*16+k)*2+c)*4096 + row], seg<16,
//       c=0 re / 1 im, row = b*64 + in_ch
//   bas [2097152, 2359296): bf16 basis tables as ushort bits (dft fragment order)
// Order: prep writes bas -> dft reads bas, writes Xp -> mix reads Xp ->
// synth reads only yc/registers and overwrites all of d_out (no race).

__device__ __forceinline__ void split8(const float* v, short8& h, short8& l) {
#pragma unroll
    for (int j = 0; j < 8; ++j) {
        unsigned u = __float_as_uint(v[j]);
        h[j] = (short)(u >> 16);                     // truncated bf16 hi
        float lo = v[j] - __uint_as_float(u & 0xffff0000u);
        unsigned ul = __float_as_uint(lo);
        l[j] = (short)((ul + 0x7fffu + ((ul >> 16) & 1u)) >> 16);  // RNE lo
    }
}

__global__ __launch_bounds__(256) void prep_kernel(const float* __restrict__ wr,
                                                   const float* __restrict__ wi,
                                                   float* __restrict__ wtr,
                                                   float* __restrict__ wti,
                                                   ushort* __restrict__ bas) {
    const int bid = blockIdx.x, t = threadIdx.x;
    if (bid < 256) {
        int idx = bid * 256 + t;                    // [0, 65536)
        int i = idx >> 10, o = (idx >> 4) & 63, k = idx & 15;
        int dst = k * 4096 + i * 64 + o;
        wtr[dst] = wr[idx];
        wti[dst] = wi[idx];
    } else {
        int e = (bid - 256) * 256 + t;              // [0, 262144)
        int j = e & 7;
        int lane = (e >> 3) & 63;
        int gk = (e >> 9) & 255;
        int ct = e >> 17;                           // 0: cos tile, 1: -sin tile
        int m = lane & 15;
        int n = gk * 32 + ((lane >> 4) & 3) * 8 + j;
        int p = (m * n) & 8191;
        float a = (float)p * (1.0f / 4096.0f);
        float v = ct ? -sinpif(a) : cospif(a);
        unsigned u = __float_as_uint(v);
        unsigned hb = (u + 0x7fffu + ((u >> 16) & 1u)) >> 16;
        float hf = __uint_as_float(hb << 16);
        float lo = v - hf;
        unsigned ul = __float_as_uint(lo);
        unsigned lb = (ul + 0x7fffu + ((ul >> 16) & 1u)) >> 16;
        bas[e] = (ushort)hb;
        bas[262144 + e] = (ushort)lb;
    }
}

// Stage 1: truncated DFT as MFMA GEMM.
// grid 1024 = 64 row-blocks(64 rows) x 16 k-segments(512 pts).
__global__ __launch_bounds__(256) void dft_kernel(const float* __restrict__ x,
                                                  const ushort* __restrict__ bas,
                                                  float* __restrict__ Xp) {
    const int t = threadIdx.x;
    const int lane = t & 63, w = t >> 6;
    const int rb = blockIdx.x >> 4, seg = blockIdx.x & 15;
    const int rowq = lane >> 4;                     // 0..3 (k-slot quarter)
    const int row = rb * 64 + w * 16 + (lane & 15);
    const float* xp = x + (size_t)row * NPTS + seg * 512 + rowq * 8;
    const bf16x8* bh = (const bf16x8*)bas;
    const bf16x8* bl = (const bf16x8*)(bas + 262144);
    const int gk0 = seg * 16;

    f32x4 acc0 = {0.f, 0.f, 0.f, 0.f};             // cos tile  (re)
    f32x4 acc1 = {0.f, 0.f, 0.f, 0.f};             // -sin tile (im)

    float4 xa = *(const float4*)xp;
    float4 xb = *(const float4*)(xp + 4);
    bf16x8 c0h = bh[gk0 * 64 + lane];
    bf16x8 c1h = bh[(256 + gk0) * 64 + lane];
    bf16x8 c0l = bl[gk0 * 64 + lane];
    bf16x8 c1l = bl[(256 + gk0) * 64 + lane];

    for (int ks = 0; ks < 16; ++ks) {
        float v[8] = {xa.x, xa.y, xa.z, xa.w, xb.x, xb.y, xb.z, xb.w};
        short8 hsv, lsv;
        split8(v, hsv, lsv);
        bf16x8 ah = __builtin_bit_cast(bf16x8, hsv);
        bf16x8 al = __builtin_bit_cast(bf16x8, lsv);

        float4 nxa, nxb;
        bf16x8 n0h, n1h, n0l, n1l;
        if (ks < 15) {
            const float* xq = xp + (ks + 1) * 32;
            nxa = *(const float4*)xq;
            nxb = *(const float4*)(xq + 4);
            int gk = gk0 + ks + 1;
            n0h = bh[gk * 64 + lane];
            n1h = bh[(256 + gk) * 64 + lane];
            n0l = bl[gk * 64 + lane];
            n1l = bl[(256 + gk) * 64 + lane];
        }

        acc0 = __builtin_amdgcn_mfma_f32_16x16x32_bf16(ah, c0h, acc0, 0, 0, 0);
        acc1 = __builtin_amdgcn_mfma_f32_16x16x32_bf16(ah, c1h, acc1, 0, 0, 0);
        acc0 = __builtin_amdgcn_mfma_f32_16x16x32_bf16(al, c0h, acc0, 0, 0, 0);
        acc1 = __builtin_amdgcn_mfma_f32_16x16x32_bf16(al, c1h, acc1, 0, 0, 0);
        acc0 = __builtin_amdgcn_mfma_f32_16x16x32_bf16(ah, c0l, acc0, 0, 0, 0);
        acc1 = __builtin_amdgcn_mfma_f32_16x16x32_bf16(ah, c1l, acc1, 0, 0, 0);

        if (ks < 15) {
            xa = nxa; xb = nxb;
            c0h = n0h; c1h = n1h; c0l = n0l; c1l = n1l;
        }
    }

    const int k = lane & 15;
    const int rbase = rb * 64 + w * 16 + rowq * 4;  // 4 consecutive rows
    *(f32x4*)&Xp[(size_t)((seg * 16 + k) * 2 + 0) * 4096 + rbase] = acc0;
    *(f32x4*)&Xp[(size_t)((seg * 16 + k) * 2 + 1) * 4096 + rbase] = acc1;
}

// Stage 2: channel mix. grid 256 = 16 modes x 16 batch-16ths (4 batches each).
// One complex output per thread: bt = t>>6 (local batch), o = t&63 (out_ch).
__global__ __launch_bounds__(256) void mix_kernel(const float* __restrict__ Xp,
                                                  const float* __restrict__ wtr,
                                                  const float* __restrict__ wti,
                                                  float* __restrict__ yc) {
    __shared__ float xre[256], xim[256];
    __shared__ float wlr[4096], wli[4096];
    const int t = threadIdx.x;
    const int k = blockIdx.x & 15, bq = blockIdx.x >> 4;
    {
        int row = bq * 256 + t;
        float re = 0.f, im = 0.f;
#pragma unroll
        for (int s = 0; s < 16; ++s) {
            re += Xp[((s * 16 + k) * 2 + 0) * 4096 + row];
            im += Xp[((s * 16 + k) * 2 + 1) * 4096 + row];
        }
        xre[t] = re;
        xim[t] = im;
#pragma unroll
        for (int j = 0; j < 4; ++j) {
            ((float4*)wlr)[t + j * 256] = ((const float4*)(wtr + k * 4096))[t + j * 256];
            ((float4*)wli)[t + j * 256] = ((const float4*)(wti + k * 4096))[t + j * 256];
        }
    }
    __syncthreads();
    const int bt = t >> 6;                      // local batch 0..3 (= wave id)
    const int o = t & 63;                       // out_ch
    float accr = 0.f, acci = 0.f;
#pragma unroll 8
    for (int i = 0; i < 64; ++i) {
        float xr = xre[bt * 64 + i], xi = xim[bt * 64 + i];   // broadcast
        float wr = wlr[i * 64 + o], wi = wli[i * 64 + o];     // stride-1
        accr += xr * wr - xi * wi;
        acci += xr * wi + xi * wr;
    }
    const float invn = 1.0f / 8192.0f;
    int row2 = (bq * 4 + bt) * 64 + o;
    if (k == 0) {
        yc[row2 * 32]      = accr * invn;
        yc[row2 * 32 + 16] = 0.f;
    } else {
        yc[row2 * 32 + k]      = 2.f * accr * invn;
        yc[row2 * 32 + 16 + k] = -2.f * acci * invn;
    }
}

// Stage 3: synthesis as MFMA GEMM: out[4096 rows, 8192 n] = coef[4096,32]*basis[32,8192].
// Swapped operands: A = basis (M=n-tile), B = coef (N=16 rows) -> D rows are 4
// consecutive n per lane -> coalesced f32x4 stores.
// grid 1024 = 256 rowgroups(16 rows) x 4 n-quarters; wave w owns 512 n (32 tiles).
// Basis kept in registers as (val,aux) pairs, rotated per 16-n tile:
//   val' = val*cd - aux*sd ; aux' = aux*cd + val*sd   (sign-normalized, uniform).
__global__ __launch_bounds__(256) void synth_kernel(const float* __restrict__ yc,
                                                    float* __restrict__ out) {
    const int t = threadIdx.x;
    const int lane = t & 63, w = t >> 6;
    const int rg = blockIdx.x >> 2, nq = blockIdx.x & 3;
    const int rowbase = rg * 16;
    const int col = lane & 15;                  // A: n within tile / B: out-row
    const int q = lane >> 4;                    // k-slot quarter
    const int fb = (q & 1) * 8;                 // frequency base of this quarter
    const bool isSin = q >= 2;                  // slots 16..31 are sin coefs

    // B-frag: coefs of out-row rowbase+col, k-slots q*8 .. q*8+7 (hi/lo split)
    bf16x8 bhf, blf;
    {
        float v[8];
        const float* cp = yc + (rowbase + col) * 32 + q * 8;
        *(float4*)&v[0] = *(const float4*)cp;
        *(float4*)&v[4] = *(const float4*)(cp + 4);
        short8 h, l;
        split8(v, h, l);
        bhf = __builtin_bit_cast(bf16x8, h);
        blf = __builtin_bit_cast(bf16x8, l);
    }

    // A basis state: per slot j, value + rotation partner + per-tile rotation
    float val[8], aux[8], cd[8], sd[8];
    const int nbase = nq * 2048 + w * 512;
    {
        int n = nbase + col;
#pragma unroll
        for (int j = 0; j < 8; ++j) {
            int fj = fb + j;
            float a = (float)((fj * n) & 8191) * (1.0f / 4096.0f);
            float c = cospif(a), s = sinpif(a);
            val[j] = isSin ? s : c;
            aux[j] = isSin ? -c : s;
            float b = (float)fj * (1.0f / 256.0f);   // delta = 2*pi*16*fj/8192
            cd[j] = cospif(b);
            sd[j] = sinpif(b);
        }
    }

    float* op = out + (size_t)(rowbase + col) * NPTS + nbase + q * 4;
#pragma unroll 4
    for (int it = 0; it < 32; ++it) {
        short8 h, l;
        split8(val, h, l);
        bf16x8 ah = __builtin_bit_cast(bf16x8, h);
        bf16x8 al = __builtin_bit_cast(bf16x8, l);
        f32x4 acc = {0.f, 0.f, 0.f, 0.f};
        acc = __builtin_amdgcn_mfma_f32_16x16x32_bf16(ah, bhf, acc, 0, 0, 0);
        acc = __builtin_amdgcn_mfma_f32_16x16x32_bf16(al, bhf, acc, 0, 0, 0);
        acc = __builtin_amdgcn_mfma_f32_16x16x32_bf16(ah, blf, acc, 0, 0, 0);
        *(f32x4*)(op + it * 16) = acc;
#pragma unroll
        for (int j = 0; j < 8; ++j) {
            float nv = val[j] * cd[j] - aux[j] * sd[j];
            float na = aux[j] * cd[j] + val[j] * sd[j];
            val[j] = nv;
            aux[j] = na;
        }
    }
}

extern "C" void kernel_launch(void* const* d_in, const int* in_sizes, int n_in,
                              void* d_out, int out_size, void* d_ws, size_t ws_size,
                              hipStream_t stream) {
    const float* x  = (const float*)d_in[0];
    const float* wr = (const float*)d_in[1];
    const float* wi = (const float*)d_in[2];
    float* out = (float*)d_out;
    float* ws  = (float*)d_ws;
    float* yc  = ws;
    float* wtr = ws + 131072;
    float* wti = ws + 196608;
    float* Xp  = out;                                // 8 MB scratch
    ushort* bas = (ushort*)(out + 2097152);          // 1 MB bf16 basis tables

    prep_kernel<<<1280, 256, 0, stream>>>(wr, wi, wtr, wti, bas);
    dft_kernel<<<1024, 256, 0, stream>>>(x, bas, Xp);
    mix_kernel<<<256, 256, 0, stream>>>(Xp, wtr, wti, yc);
    synth_kernel<<<1024, 256, 0, stream>>>(yc, out);
}

// Round 3
// 257.072 us; speedup vs baseline: 1.2070x; 1.0047x over previous
//
#include <hip/hip_runtime.h>

#define NPTS 8192

typedef __bf16 bf16x8 __attribute__((ext_vector_type(8)));
typedef short short8 __attribute__((ext_vector_type(8)));
typedef float f32x4 __attribute__((ext_vector_type(4)));

// ws layout (floats): yc [0,131072) ; wtr [131072,196608) ; wti [196608,262144)
// d_out scratch layout (floats):
//   Xp  [0, 2097152): partial DFT, Xp[((seg*16+k)*2+c)*4096 + row], seg<16,
//       c=0 re / 1 im, row = b*64 + in_ch
//   bas [2097152, 2359296): bf16 basis tables as ushort bits (dft fragment order)
// Order: prep writes bas -> dft reads bas, writes Xp -> mix reads Xp ->
// synth reads only yc/registers and overwrites all of d_out (no race).

__device__ __forceinline__ void split8(const float* v, short8& h, short8& l) {
#pragma unroll
    for (int j = 0; j < 8; ++j) {
        unsigned u = __float_as_uint(v[j]);
        h[j] = (short)(u >> 16);                     // truncated bf16 hi
        float lo = v[j] - __uint_as_float(u & 0xffff0000u);
        unsigned ul = __float_as_uint(lo);
        l[j] = (short)((ul + 0x7fffu + ((ul >> 16) & 1u)) >> 16);  // RNE lo
    }
}

__global__ __launch_bounds__(256) void prep_kernel(const float* __restrict__ wr,
                                                   const float* __restrict__ wi,
                                                   float* __restrict__ wtr,
                                                   float* __restrict__ wti,
                                                   ushort* __restrict__ bas) {
    const int bid = blockIdx.x, t = threadIdx.x;
    if (bid < 256) {
        int idx = bid * 256 + t;                    // [0, 65536)
        int i = idx >> 10, o = (idx >> 4) & 63, k = idx & 15;
        int dst = k * 4096 + i * 64 + o;
        wtr[dst] = wr[idx];
        wti[dst] = wi[idx];
    } else {
        int e = (bid - 256) * 256 + t;              // [0, 262144)
        int j = e & 7;
        int lane = (e >> 3) & 63;
        int gk = (e >> 9) & 255;
        int ct = e >> 17;                           // 0: cos tile, 1: -sin tile
        int m = lane & 15;
        int n = gk * 32 + ((lane >> 4) & 3) * 8 + j;
        int p = (m * n) & 8191;
        float a = (float)p * (1.0f / 4096.0f);
        float v = ct ? -sinpif(a) : cospif(a);
        unsigned u = __float_as_uint(v);
        unsigned hb = (u + 0x7fffu + ((u >> 16) & 1u)) >> 16;
        float hf = __uint_as_float(hb << 16);
        float lo = v - hf;
        unsigned ul = __float_as_uint(lo);
        unsigned lb = (ul + 0x7fffu + ((ul >> 16) & 1u)) >> 16;
        bas[e] = (ushort)hb;
        bas[262144 + e] = (ushort)lb;
    }
}

// Stage 1: truncated DFT as MFMA GEMM.
// grid 1024 = 64 row-blocks(64 rows) x 16 k-segments(512 pts).
// v3: K-loop in 4-step bursts -> per row a wave issues 512B of CONTIGUOUS
// reads back-to-back (was 128B per step), register double-buffered.
__global__ __launch_bounds__(256) void dft_kernel(const float* __restrict__ x,
                                                  const ushort* __restrict__ bas,
                                                  float* __restrict__ Xp) {
    const int t = threadIdx.x;
    const int lane = t & 63, w = t >> 6;
    const int rb = blockIdx.x >> 4, seg = blockIdx.x & 15;
    const int rowq = lane >> 4;                     // 0..3 (k-slot quarter)
    const int row = rb * 64 + w * 16 + (lane & 15);
    const float* xp = x + (size_t)row * NPTS + seg * 512 + rowq * 8;
    const bf16x8* bh = (const bf16x8*)bas;
    const bf16x8* bl = (const bf16x8*)(bas + 262144);
    const int gk0 = seg * 16;

    f32x4 acc0 = {0.f, 0.f, 0.f, 0.f};             // cos tile  (re)
    f32x4 acc1 = {0.f, 0.f, 0.f, 0.f};             // -sin tile (im)

    float4 xc[8], xn[8];                            // cur / next burst x
    bf16x8 c0h, c1h, c0l, c1l;                      // cur-step basis frags

#pragma unroll
    for (int j = 0; j < 4; ++j) {                   // burst 0: contiguous 512B/row
        xc[j * 2]     = *(const float4*)(xp + j * 32);
        xc[j * 2 + 1] = *(const float4*)(xp + j * 32 + 4);
    }
    c0h = bh[gk0 * 64 + lane];
    c1h = bh[(256 + gk0) * 64 + lane];
    c0l = bl[gk0 * 64 + lane];
    c1l = bl[(256 + gk0) * 64 + lane];

#pragma unroll
    for (int b = 0; b < 4; ++b) {
        if (b < 3) {                                // next-burst x: 8 loads, contiguous
#pragma unroll
            for (int j = 0; j < 4; ++j) {
                const float* q = xp + (b + 1) * 128 + j * 32;
                xn[j * 2]     = *(const float4*)q;
                xn[j * 2 + 1] = *(const float4*)(q + 4);
            }
        }
#pragma unroll
        for (int ks = 0; ks < 4; ++ks) {
            // next-step basis prefetch (L2-resident; &255 keeps in-bounds at tail)
            int gkn = (gk0 + b * 4 + ks + 1) & 255;
            bf16x8 n0h = bh[gkn * 64 + lane];
            bf16x8 n1h = bh[(256 + gkn) * 64 + lane];
            bf16x8 n0l = bl[gkn * 64 + lane];
            bf16x8 n1l = bl[(256 + gkn) * 64 + lane];

            float v[8];
            float4 va = xc[ks * 2], vb = xc[ks * 2 + 1];
            v[0] = va.x; v[1] = va.y; v[2] = va.z; v[3] = va.w;
            v[4] = vb.x; v[5] = vb.y; v[6] = vb.z; v[7] = vb.w;
            short8 hsv, lsv;
            split8(v, hsv, lsv);
            bf16x8 ah = __builtin_bit_cast(bf16x8, hsv);
            bf16x8 al = __builtin_bit_cast(bf16x8, lsv);

            // D = xh*bh + xl*bh + xh*bl   (drop lo*lo, ~2^-18 rel)
            acc0 = __builtin_amdgcn_mfma_f32_16x16x32_bf16(ah, c0h, acc0, 0, 0, 0);
            acc1 = __builtin_amdgcn_mfma_f32_16x16x32_bf16(ah, c1h, acc1, 0, 0, 0);
            acc0 = __builtin_amdgcn_mfma_f32_16x16x32_bf16(al, c0h, acc0, 0, 0, 0);
            acc1 = __builtin_amdgcn_mfma_f32_16x16x32_bf16(al, c1h, acc1, 0, 0, 0);
            acc0 = __builtin_amdgcn_mfma_f32_16x16x32_bf16(ah, c0l, acc0, 0, 0, 0);
            acc1 = __builtin_amdgcn_mfma_f32_16x16x32_bf16(ah, c1l, acc1, 0, 0, 0);

            c0h = n0h; c1h = n1h; c0l = n0l; c1l = n1l;
        }
        if (b < 3) {
#pragma unroll
            for (int j = 0; j < 8; ++j) xc[j] = xn[j];
        }
    }

    const int k = lane & 15;
    const int rbase = rb * 64 + w * 16 + rowq * 4;  // 4 consecutive rows
    *(f32x4*)&Xp[(size_t)((seg * 16 + k) * 2 + 0) * 4096 + rbase] = acc0;
    *(f32x4*)&Xp[(size_t)((seg * 16 + k) * 2 + 1) * 4096 + rbase] = acc1;
}

// Stage 2: channel mix. grid 256 = 16 modes x 16 batch-16ths (4 batches each).
// One complex output per thread: bt = t>>6 (local batch), o = t&63 (out_ch).
__global__ __launch_bounds__(256) void mix_kernel(const float* __restrict__ Xp,
                                                  const float* __restrict__ wtr,
                                                  const float* __restrict__ wti,
                                                  float* __restrict__ yc) {
    __shared__ float xre[256], xim[256];
    __shared__ float wlr[4096], wli[4096];
    const int t = threadIdx.x;
    const int k = blockIdx.x & 15, bq = blockIdx.x >> 4;
    {
        int row = bq * 256 + t;
        float re = 0.f, im = 0.f;
#pragma unroll
        for (int s = 0; s < 16; ++s) {
            re += Xp[((s * 16 + k) * 2 + 0) * 4096 + row];
            im += Xp[((s * 16 + k) * 2 + 1) * 4096 + row];
        }
        xre[t] = re;
        xim[t] = im;
#pragma unroll
        for (int j = 0; j < 4; ++j) {
            ((float4*)wlr)[t + j * 256] = ((const float4*)(wtr + k * 4096))[t + j * 256];
            ((float4*)wli)[t + j * 256] = ((const float4*)(wti + k * 4096))[t + j * 256];
        }
    }
    __syncthreads();
    const int bt = t >> 6;                      // local batch 0..3 (= wave id)
    const int o = t & 63;                       // out_ch
    float accr = 0.f, acci = 0.f;
#pragma unroll 8
    for (int i = 0; i < 64; ++i) {
        float xr = xre[bt * 64 + i], xi = xim[bt * 64 + i];   // broadcast
        float wr = wlr[i * 64 + o], wi = wli[i * 64 + o];     // stride-1
        accr += xr * wr - xi * wi;
        acci += xr * wi + xi * wr;
    }
    const float invn = 1.0f / 8192.0f;
    int row2 = (bq * 4 + bt) * 64 + o;
    if (k == 0) {
        yc[row2 * 32]      = accr * invn;
        yc[row2 * 32 + 16] = 0.f;
    } else {
        yc[row2 * 32 + k]      = 2.f * accr * invn;
        yc[row2 * 32 + 16 + k] = -2.f * acci * invn;
    }
}

// Stage 3: synthesis as MFMA GEMM: out[4096 rows, 8192 n] = coef[4096,32]*basis[32,8192].
// Swapped operands: A = basis (M=n-tile), B = coef (N=16 rows) -> D rows are 4
// consecutive n per lane -> coalesced f32x4 stores.
// grid 1024 = 256 rowgroups(16 rows) x 4 n-quarters; wave w owns 512 n (32 tiles).
// Basis kept in registers as (val,aux) pairs, rotated per 16-n tile:
//   val' = val*cd - aux*sd ; aux' = aux*cd + val*sd   (sign-normalized, uniform).
__global__ __launch_bounds__(256) void synth_kernel(const float* __restrict__ yc,
                                                    float* __restrict__ out) {
    const int t = threadIdx.x;
    const int lane = t & 63, w = t >> 6;
    const int rg = blockIdx.x >> 2, nq = blockIdx.x & 3;
    const int rowbase = rg * 16;
    const int col = lane & 15;                  // A: n within tile / B: out-row
    const int q = lane >> 4;                    // k-slot quarter
    const int fb = (q & 1) * 8;                 // frequency base of this quarter
    const bool isSin = q >= 2;                  // slots 16..31 are sin coefs

    // B-frag: coefs of out-row rowbase+col, k-slots q*8 .. q*8+7 (hi/lo split)
    bf16x8 bhf, blf;
    {
        float v[8];
        const float* cp = yc + (rowbase + col) * 32 + q * 8;
        *(float4*)&v[0] = *(const float4*)cp;
        *(float4*)&v[4] = *(const float4*)(cp + 4);
        short8 h, l;
        split8(v, h, l);
        bhf = __builtin_bit_cast(bf16x8, h);
        blf = __builtin_bit_cast(bf16x8, l);
    }

    // A basis state: per slot j, value + rotation partner + per-tile rotation
    float val[8], aux[8], cd[8], sd[8];
    const int nbase = nq * 2048 + w * 512;
    {
        int n = nbase + col;
#pragma unroll
        for (int j = 0; j < 8; ++j) {
            int fj = fb + j;
            float a = (float)((fj * n) & 8191) * (1.0f / 4096.0f);
            float c = cospif(a), s = sinpif(a);
            val[j] = isSin ? s : c;
            aux[j] = isSin ? -c : s;
            float b = (float)fj * (1.0f / 256.0f);   // delta = 2*pi*16*fj/8192
            cd[j] = cospif(b);
            sd[j] = sinpif(b);
        }
    }

    float* op = out + (size_t)(rowbase + col) * NPTS + nbase + q * 4;
#pragma unroll 4
    for (int it = 0; it < 32; ++it) {
        short8 h, l;
        split8(val, h, l);
        bf16x8 ah = __builtin_bit_cast(bf16x8, h);
        bf16x8 al = __builtin_bit_cast(bf16x8, l);
        f32x4 acc = {0.f, 0.f, 0.f, 0.f};
        acc = __builtin_amdgcn_mfma_f32_16x16x32_bf16(ah, bhf, acc, 0, 0, 0);
        acc = __builtin_amdgcn_mfma_f32_16x16x32_bf16(al, bhf, acc, 0, 0, 0);
        acc = __builtin_amdgcn_mfma_f32_16x16x32_bf16(ah, blf, acc, 0, 0, 0);
        *(f32x4*)(op + it * 16) = acc;
#pragma unroll
        for (int j = 0; j < 8; ++j) {
            float nv = val[j] * cd[j] - aux[j] * sd[j];
            float na = aux[j] * cd[j] + val[j] * sd[j];
            val[j] = nv;
            aux[j] = na;
        }
    }
}

extern "C" void kernel_launch(void* const* d_in, const int* in_sizes, int n_in,
                              void* d_out, int out_size, void* d_ws, size_t ws_size,
                              hipStream_t stream) {
    const float* x  = (const float*)d_in[0];
    const float* wr = (const float*)d_in[1];
    const float* wi = (const float*)d_in[2];
    float* out = (float*)d_out;
    float* ws  = (float*)d_ws;
    float* yc  = ws;
    float* wtr = ws + 131072;
    float* wti = ws + 196608;
    float* Xp  = out;                                // 8 MB scratch
    ushort* bas = (ushort*)(out + 2097152);          // 1 MB bf16 basis tables

    prep_kernel<<<1280, 256, 0, stream>>>(wr, wi, wtr, wti, bas);
    dft_kernel<<<1024, 256, 0, stream>>>(x, bas, Xp);
    mix_kernel<<<256, 256, 0, stream>>>(Xp, wtr, wti, yc);
    synth_kernel<<<1024, 256, 0, stream>>>(yc, out);
}